// Round 8
// baseline (147.194 us; speedup 1.0000x reference)
//
#include <hip/hip_runtime.h>
#include <hip/hip_bf16.h>
#include <cstdint>
#include <cstddef>

#define B_ 8
#define C_ 256
#define N_ 2048
#define H_ 32
#define VP_ 2064            // vbf padded row stride (elems) = 4128 B
#define NT_ (N_ / 64)

typedef __bf16 bf8 __attribute__((ext_vector_type(8)));
typedef __bf16 bf4 __attribute__((ext_vector_type(4)));
typedef float f4 __attribute__((ext_vector_type(4)));

__device__ inline void gload_lds16(const void* g, void* l) {
  __builtin_amdgcn_global_load_lds(
      (const __attribute__((address_space(1))) unsigned int*)g,
      (__attribute__((address_space(3))) unsigned int*)l, 16, 0, 0);
}

// ---- P1: pack weights: wpk bf16 [320][256] = {wv; wq; wk}, bpk fp32 [320] ----
// wq/bq pre-scaled by log2(e): fused kernel uses raw v_exp_f32 (exp2).
__global__ __launch_bounds__(256) void pack_kernel(
    const float* __restrict__ wq, const float* __restrict__ wk,
    const float* __restrict__ wv, const float* __restrict__ bq,
    const float* __restrict__ bk, const float* __restrict__ bv,
    __hip_bfloat16* __restrict__ wpk, float* __restrict__ bpk) {
  const float L2E = 1.44269504088896f;
  int r = blockIdx.x, c = threadIdx.x;
  float v;
  if (r < 256)      v = wv[r * 256 + c];
  else if (r < 288) v = wq[(r - 256) * 256 + c] * L2E;
  else              v = wk[(r - 288) * 256 + c];
  wpk[r * 256 + c] = __float2bfloat16(v);
  if (c == 0) bpk[r] = (r < 256) ? bv[r] : (r < 288 ? bq[r - 256] * L2E : bk[r - 288]);
}

// ---- P2: proj GEMM v4: BOTH streams 2+ bodies deep.
// wpk: 3-buffer As, staged 2 bodies ahead. x: 4-buffer xS, staged 3 ahead.
// Issue log (oldest->newest): x0 w0x5 x1 w1x5 x2 | body t: w(t+2)x5, x(t+3).
// Top of body t: outstanding = [w(t)x5, x(t+1), w(t+1)x5, x(t+2)];
// vmcnt(7) completes w(t)+x(t), leaves x(t+1)+w(t+1)x5+x(t+2) in flight:
// wpk gets 2 full bodies of latency cover (vs 1 in R7, 0 in R1).
__global__ __launch_bounds__(256) void proj_kernel(
    const float* __restrict__ x, const __hip_bfloat16* __restrict__ wpk,
    const float* __restrict__ bpk, __hip_bfloat16* __restrict__ vbf,
    __hip_bfloat16* __restrict__ qkb) {
  __shared__ __attribute__((aligned(16))) __hip_bfloat16 As[3][320 * 32];  // 60 KB
  __shared__ __attribute__((aligned(16))) float xS[4][32 * 32];            // 16 KB
  int tid = threadIdx.x, wv = tid >> 6, lane = tid & 63;
  int b = blockIdx.y;
  int n0 = blockIdx.x * 32;
  int fcol = lane & 15, hi4 = lane >> 4;
  int grow = lane >> 2, gc = (lane & 3) * 8;               // wpk staging
  int xrow = wv * 8 + (lane >> 3), xcq = (lane & 7) * 4;   // x staging
  const float* xb = x + (size_t)b * C_ * N_;

#define STAGE_W(T)                                                            \
  _Pragma("unroll")                                                           \
  for (int g = 0; g < 5; ++g)                                                 \
    gload_lds16(wpk + (size_t)(wv * 80 + g * 16 + grow) * 256 + (T) * 32 + gc,\
                &As[(T) % 3][(wv * 80 + g * 16) * 32]);
#define STAGE_X(T)                                                            \
  gload_lds16(xb + (size_t)((T) * 32 + xrow) * N_ + n0 + xcq,                 \
              &xS[(T) % 4][wv * 8 * 32]);

  // prologue order: x0, w0, x1, w1, x2
  STAGE_X(0)
  STAGE_W(0)
  STAGE_X(1)
  STAGE_W(1)
  STAGE_X(2)

  f4 acc[5][2] = {};
#pragma unroll
  for (int t = 0; t < 8; ++t) {
    if (t < 6)      asm volatile("s_waitcnt vmcnt(7)" ::: "memory");
    else if (t == 6) asm volatile("s_waitcnt vmcnt(6)" ::: "memory");
    else            asm volatile("s_waitcnt vmcnt(0)" ::: "memory");
    __builtin_amdgcn_s_barrier();
    __builtin_amdgcn_sched_barrier(0);
    if (t + 2 <= 7) { STAGE_W(t + 2) }
    if (t + 3 <= 7) { STAGE_X(t + 3) }
    const float* xt = &xS[t % 4][0];
    bf8 bfr[2];
#pragma unroll
    for (int j = 0; j < 2; ++j)
#pragma unroll
      for (int e = 0; e < 8; ++e)
        bfr[j][e] = (__bf16)xt[(hi4 * 8 + e) * 32 + j * 16 + fcol];
#pragma unroll
    for (int s = 0; s < 5; ++s) {
      bf8 af = *(const bf8*)&As[t % 3][(wv * 80 + s * 16 + fcol) * 32 + hi4 * 8];
      acc[s][0] = __builtin_amdgcn_mfma_f32_16x16x32_bf16(af, bfr[0], acc[s][0], 0, 0, 0);
      acc[s][1] = __builtin_amdgcn_mfma_f32_16x16x32_bf16(af, bfr[1], acc[s][1], 0, 0, 0);
    }
  }
#undef STAGE_W
#undef STAGE_X
  int rq = hi4 * 4;
#pragma unroll
  for (int s = 0; s < 5; ++s)
#pragma unroll
    for (int r = 0; r < 4; ++r) {
      int m = wv * 80 + s * 16 + rq + r;
      float bias = bpk[m];
#pragma unroll
      for (int j = 0; j < 2; ++j) {
        int n = n0 + j * 16 + fcol;
        float val = acc[s][j][r] + bias;
        if (m < 256)
          vbf[((size_t)b * C_ + m) * VP_ + n] = __float2bfloat16(val);
        else
          qkb[((size_t)b * N_ + n) * 64 + (m - 256)] = __float2bfloat16(val);
      }
    }
}

// ---- fused attention v10: i-split for 2x occupancy at CONSTANT work.
// Grid 1024 (4 blocks/CU, 16 waves/CU): block = c128 x i32, 4 waves.
// Wave wv: j-strip wv*16 of S (2 mfma16) + PV c-rows [wv*32,+32) (8 mfma16).
// Per-CU totals (MFMA, LDS bytes, VALU) identical to v8 -- pure TLP doubling.
// Keeps v8's cross-barrier pipeline: body t reads P(t) (published by prev
// barrier), computes S(t+1), prefetches K/V(t+2), PV(t), packs P(t+1),
// lgkm-only drain + barrier.
#define MFMA16(A, B, C) __builtin_amdgcn_mfma_f32_16x16x32_bf16(A, B, C, 0, 0, 0)

#define ATTN_BODY(T, BUF, KC, KN, VA, VB, VC, VD)                              \
  {                                                                            \
    bf8 pf00 = *(const bf8*)&pS[BUF][ 0 + li][ 0 + lg8];                       \
    bf8 pf10 = *(const bf8*)&pS[BUF][16 + li][ 0 + lg8];                       \
    bf8 pf01 = *(const bf8*)&pS[BUF][ 0 + li][32 + lg8];                       \
    bf8 pf11 = *(const bf8*)&pS[BUF][16 + li][32 + lg8];                       \
    f4 s0 = {}, s1 = {};                                                       \
    if ((T) + 1 < NT_) {                                                       \
      s0 = MFMA16(KC, qf0, s0);                                                \
      s1 = MFMA16(KC, qf1, s1);                                                \
    }                                                                          \
    {                                                                          \
      int tn_ = (T) + 2 < NT_ ? (T) + 2 : NT_ - 1;                             \
      KN = *(const bf8*)(kp + (size_t)tn_ * 64 * 64);                          \
    }                                                                          \
    __builtin_amdgcn_s_setprio(1);                                             \
    acc[0][0] = MFMA16(VA, pf00, acc[0][0]);                                   \
    acc[0][1] = MFMA16(VA, pf10, acc[0][1]);                                   \
    acc[1][0] = MFMA16(VC, pf00, acc[1][0]);                                   \
    acc[1][1] = MFMA16(VC, pf10, acc[1][1]);                                   \
    acc[0][0] = MFMA16(VB, pf01, acc[0][0]);                                   \
    acc[0][1] = MFMA16(VB, pf11, acc[0][1]);                                   \
    acc[1][0] = MFMA16(VD, pf01, acc[1][0]);                                   \
    acc[1][1] = MFMA16(VD, pf11, acc[1][1]);                                   \
    __builtin_amdgcn_s_setprio(0);                                             \
    {                                                                          \
      int tn_ = (T) + 2 < NT_ ? (T) + 2 : NT_ - 1;                             \
      const __hip_bfloat16* vpn_ = vR + tn_ * 64;                              \
      VA = *(const bf8*)vpn_;                                                  \
      VB = *(const bf8*)(vpn_ + 32);                                           \
      VC = *(const bf8*)(vpn_ + 16 * VP_);                                     \
      VD = *(const bf8*)(vpn_ + 16 * VP_ + 32);                                \
    }                                                                          \
    if ((T) + 1 < NT_) {                                                       \
      _Pragma("unroll")                                                        \
      for (int m = 0; m < 4; ++m) {                                            \
        s0[m] = __builtin_amdgcn_exp2f(s0[m]);                                 \
        s1[m] = __builtin_amdgcn_exp2f(s1[m]);                                 \
      }                                                                        \
      lp0 += s0[0] + s0[1] + s0[2] + s0[3];                                    \
      lp1 += s1[0] + s1[1] + s1[2] + s1[3];                                    \
      bf4 t0, t1;                                                              \
      _Pragma("unroll")                                                        \
      for (int m = 0; m < 4; ++m) { t0[m] = (__bf16)s0[m]; t1[m] = (__bf16)s1[m]; } \
      *(bf4*)&pS[(BUF) ^ 1][ 0 + li][wv * 16 + lg4] = t0;                      \
      *(bf4*)&pS[(BUF) ^ 1][16 + li][wv * 16 + lg4] = t1;                      \
      asm volatile("s_waitcnt lgkmcnt(0)" ::: "memory");                       \
      __builtin_amdgcn_sched_barrier(0);                                       \
      __builtin_amdgcn_s_barrier();                                            \
      __builtin_amdgcn_sched_barrier(0);                                       \
    }                                                                          \
  }

__global__ __launch_bounds__(256, 4) void fused_attn(
    const __hip_bfloat16* __restrict__ qk,   // [b][n][64]: q 0..31, k 32..63
    const __hip_bfloat16* __restrict__ vbf,  // [b][c][VP_]
    const float* __restrict__ x, float* __restrict__ out) {
  __shared__ __attribute__((aligned(16))) __hip_bfloat16 pS[2][32][72];  // 9 KB
  __shared__ float lSp[4][32];
  int tid = threadIdx.x;
  int wv = tid >> 6, lane = tid & 63;
  int li = lane & 15, lg = lane >> 4;
  int lg8 = lg * 8, lg4 = lg * 4;
  // XCD-pinning: b = blk&7 pins batch b's 128 blocks to one XCD's L2.
  int blk = blockIdx.x;
  int b = blk & 7;
  int rest = blk >> 3;         // 0..127
  int c0 = (rest & 1) * 128;
  int i0 = (rest >> 1) * 32;   // i-tile of 32

  const __hip_bfloat16* qkB = qk + (size_t)b * N_ * 64;
  // Q B-frags: col i = i0 + is*16 + li, k = h = lg*8+e
  bf8 qf0 = *(const bf8*)&qkB[(size_t)(i0 +  0 + li) * 64 + lg8];
  bf8 qf1 = *(const bf8*)&qkB[(size_t)(i0 + 16 + li) * 64 + lg8];
  // K A-frag base: row j = t*64 + wv*16 + li (this wave's j-strip), k = h
  const __hip_bfloat16* kp = qkB + (size_t)(wv * 16 + li) * 64 + 32 + lg8;
  // V A-frag base: row c = c0 + wv*32 + cs*16 + li, k = j = t*64 + kc*32 + lg*8
  const __hip_bfloat16* vR =
      vbf + ((size_t)b * C_ + c0 + wv * 32 + li) * VP_ + lg8;

  // Prologue: K(0) transient; K(1)->kO; V(0)->vE; V(1)->vO.
  bf8 k00 = *(const bf8*)kp;
  bf8 kO = *(const bf8*)(kp + 64 * 64);
  bf8 kE;
  bf8 vEA = *(const bf8*)vR;
  bf8 vEB = *(const bf8*)(vR + 32);
  bf8 vEC = *(const bf8*)(vR + 16 * VP_);
  bf8 vED = *(const bf8*)(vR + 16 * VP_ + 32);
  bf8 vOA = *(const bf8*)(vR + 64);
  bf8 vOB = *(const bf8*)(vR + 64 + 32);
  bf8 vOC = *(const bf8*)(vR + 16 * VP_ + 64);
  bf8 vOD = *(const bf8*)(vR + 16 * VP_ + 64 + 32);

  f4 acc[2][2] = {};
  float lp0 = 0.f, lp1 = 0.f;

  // Prologue S(0): exp2, pack, publish P(0) -> pS[0]
  {
    f4 s0 = {}, s1 = {};
    s0 = MFMA16(k00, qf0, s0);
    s1 = MFMA16(k00, qf1, s1);
#pragma unroll
    for (int m = 0; m < 4; ++m) {
      s0[m] = __builtin_amdgcn_exp2f(s0[m]);
      s1[m] = __builtin_amdgcn_exp2f(s1[m]);
    }
    lp0 += s0[0] + s0[1] + s0[2] + s0[3];
    lp1 += s1[0] + s1[1] + s1[2] + s1[3];
    bf4 t0, t1;
#pragma unroll
    for (int m = 0; m < 4; ++m) { t0[m] = (__bf16)s0[m]; t1[m] = (__bf16)s1[m]; }
    *(bf4*)&pS[0][ 0 + li][wv * 16 + lg4] = t0;
    *(bf4*)&pS[0][16 + li][wv * 16 + lg4] = t1;
    asm volatile("s_waitcnt lgkmcnt(0)" ::: "memory");
    __builtin_amdgcn_sched_barrier(0);
    __builtin_amdgcn_s_barrier();
    __builtin_amdgcn_sched_barrier(0);
  }

  for (int tt = 0; tt < NT_; tt += 2) {
    ATTN_BODY(tt,     0, kO, kE, vEA, vEB, vEC, vED)
    ATTN_BODY(tt + 1, 1, kE, kO, vOA, vOB, vOC, vOD)
  }
#undef ATTN_BODY

  // Denominator: reduce over lg (shfl 16,32), combine 4 j-strips via LDS.
  lp0 += __shfl_xor(lp0, 16); lp0 += __shfl_xor(lp0, 32);
  lp1 += __shfl_xor(lp1, 16); lp1 += __shfl_xor(lp1, 32);
  if (lane < 16) { lSp[wv][lane] = lp0; lSp[wv][16 + lane] = lp1; }
  __syncthreads();
  float linv0 = 1.0f / (lSp[0][li] + lSp[1][li] + lSp[2][li] + lSp[3][li]);
  float linv1 = 1.0f / (lSp[0][16 + li] + lSp[1][16 + li] +
                        lSp[2][16 + li] + lSp[3][16 + li]);

  const float* xr = x + (size_t)b * C_ * N_;
  float* op = out + (size_t)b * C_ * N_;
#pragma unroll
  for (int cs = 0; cs < 2; ++cs)
#pragma unroll
    for (int m = 0; m < 4; ++m) {
      int c = c0 + wv * 32 + cs * 16 + lg4 + m;
      size_t base = (size_t)c * N_ + i0;
      op[base +  0 + li] = acc[cs][0][m] * linv0 + xr[base +  0 + li];
      op[base + 16 + li] = acc[cs][1][m] * linv1 + xr[base + 16 + li];
    }
}

extern "C" void kernel_launch(void* const* d_in, const int* in_sizes, int n_in,
                              void* d_out, int out_size, void* d_ws, size_t ws_size,
                              hipStream_t stream) {
  const float* x  = (const float*)d_in[0];
  const float* wq = (const float*)d_in[1];
  const float* bq = (const float*)d_in[2];
  const float* wk = (const float*)d_in[3];
  const float* bk = (const float*)d_in[4];
  const float* wv = (const float*)d_in[5];
  const float* bv = (const float*)d_in[6];
  float* out = (float*)d_out;

  char* ws = (char*)d_ws;
  __hip_bfloat16* qkb = (__hip_bfloat16*)ws;                        // 2 MiB [b][n][64]
  __hip_bfloat16* vbf = (__hip_bfloat16*)(ws + (2u << 20));         // 8.06 MiB [b][c][VP_]
  __hip_bfloat16* wpk = (__hip_bfloat16*)(ws + 10551296u);          // 160 KiB [320][256]
  float*          bpk = (float*)(ws + 10551296u + 163840u);

  pack_kernel<<<dim3(320), 256, 0, stream>>>(wq, wk, wv, bq, bk, bv, wpk, bpk);
  proj_kernel<<<dim3(N_ / 32, B_), 256, 0, stream>>>(x, wpk, bpk, vbf, qkb);
  fused_attn<<<dim3(1024), 256, 0, stream>>>(qkb, vbf, x, out);
}

// Round 9
// 132.918 us; speedup vs baseline: 1.1074x; 1.1074x over previous
//
#include <hip/hip_runtime.h>
#include <hip/hip_bf16.h>
#include <cstdint>
#include <cstddef>

#define B_ 8
#define C_ 256
#define N_ 2048
#define H_ 32
#define VP_ 2064            // vbf padded row stride (elems) = 4128 B
#define NT_ (N_ / 64)

typedef __bf16 bf8 __attribute__((ext_vector_type(8)));
typedef __bf16 bf4 __attribute__((ext_vector_type(4)));
typedef float f4 __attribute__((ext_vector_type(4)));

__device__ inline void gload_lds16(const void* g, void* l) {
  __builtin_amdgcn_global_load_lds(
      (const __attribute__((address_space(1))) unsigned int*)g,
      (__attribute__((address_space(3))) unsigned int*)l, 16, 0, 0);
}

// ---- P1: pack weights: wpk bf16 [320][256] = {wv; wq; wk}, bpk fp32 [320] ----
// wq/bq pre-scaled by log2(e): fused kernel uses raw v_exp_f32 (exp2).
__global__ __launch_bounds__(256) void pack_kernel(
    const float* __restrict__ wq, const float* __restrict__ wk,
    const float* __restrict__ wv, const float* __restrict__ bq,
    const float* __restrict__ bk, const float* __restrict__ bv,
    __hip_bfloat16* __restrict__ wpk, float* __restrict__ bpk) {
  const float L2E = 1.44269504088896f;
  int r = blockIdx.x, c = threadIdx.x;
  float v;
  if (r < 256)      v = wv[r * 256 + c];
  else if (r < 288) v = wq[(r - 256) * 256 + c] * L2E;
  else              v = wk[(r - 288) * 256 + c];
  wpk[r * 256 + c] = __float2bfloat16(v);
  if (c == 0) bpk[r] = (r < 256) ? bv[r] : (r < 288 ? bq[r - 256] * L2E : bk[r - 288]);
}

// ---- P2: proj GEMM v4 (R8, unchanged) ----
__global__ __launch_bounds__(256) void proj_kernel(
    const float* __restrict__ x, const __hip_bfloat16* __restrict__ wpk,
    const float* __restrict__ bpk, __hip_bfloat16* __restrict__ vbf,
    __hip_bfloat16* __restrict__ qkb) {
  __shared__ __attribute__((aligned(16))) __hip_bfloat16 As[3][320 * 32];  // 60 KB
  __shared__ __attribute__((aligned(16))) float xS[4][32 * 32];            // 16 KB
  int tid = threadIdx.x, wv = tid >> 6, lane = tid & 63;
  int b = blockIdx.y;
  int n0 = blockIdx.x * 32;
  int fcol = lane & 15, hi4 = lane >> 4;
  int grow = lane >> 2, gc = (lane & 3) * 8;               // wpk staging
  int xrow = wv * 8 + (lane >> 3), xcq = (lane & 7) * 4;   // x staging
  const float* xb = x + (size_t)b * C_ * N_;

#define STAGE_W(T)                                                            \
  _Pragma("unroll")                                                           \
  for (int g = 0; g < 5; ++g)                                                 \
    gload_lds16(wpk + (size_t)(wv * 80 + g * 16 + grow) * 256 + (T) * 32 + gc,\
                &As[(T) % 3][(wv * 80 + g * 16) * 32]);
#define STAGE_X(T)                                                            \
  gload_lds16(xb + (size_t)((T) * 32 + xrow) * N_ + n0 + xcq,                 \
              &xS[(T) % 4][wv * 8 * 32]);

  STAGE_X(0)
  STAGE_W(0)
  STAGE_X(1)
  STAGE_W(1)
  STAGE_X(2)

  f4 acc[5][2] = {};
#pragma unroll
  for (int t = 0; t < 8; ++t) {
    if (t < 6)      asm volatile("s_waitcnt vmcnt(7)" ::: "memory");
    else if (t == 6) asm volatile("s_waitcnt vmcnt(6)" ::: "memory");
    else            asm volatile("s_waitcnt vmcnt(0)" ::: "memory");
    __builtin_amdgcn_s_barrier();
    __builtin_amdgcn_sched_barrier(0);
    if (t + 2 <= 7) { STAGE_W(t + 2) }
    if (t + 3 <= 7) { STAGE_X(t + 3) }
    const float* xt = &xS[t % 4][0];
    bf8 bfr[2];
#pragma unroll
    for (int j = 0; j < 2; ++j)
#pragma unroll
      for (int e = 0; e < 8; ++e)
        bfr[j][e] = (__bf16)xt[(hi4 * 8 + e) * 32 + j * 16 + fcol];
#pragma unroll
    for (int s = 0; s < 5; ++s) {
      bf8 af = *(const bf8*)&As[t % 3][(wv * 80 + s * 16 + fcol) * 32 + hi4 * 8];
      acc[s][0] = __builtin_amdgcn_mfma_f32_16x16x32_bf16(af, bfr[0], acc[s][0], 0, 0, 0);
      acc[s][1] = __builtin_amdgcn_mfma_f32_16x16x32_bf16(af, bfr[1], acc[s][1], 0, 0, 0);
    }
  }
#undef STAGE_W
#undef STAGE_X
  int rq = hi4 * 4;
#pragma unroll
  for (int s = 0; s < 5; ++s)
#pragma unroll
    for (int r = 0; r < 4; ++r) {
      int m = wv * 80 + s * 16 + rq + r;
      float bias = bpk[m];
#pragma unroll
      for (int j = 0; j < 2; ++j) {
        int n = n0 + j * 16 + fcol;
        float val = acc[s][j][r] + bias;
        if (m < 256)
          vbf[((size_t)b * C_ + m) * VP_ + n] = __float2bfloat16(val);
        else
          qkb[((size_t)b * N_ + n) * 64 + (m - 256)] = __float2bfloat16(val);
      }
    }
}

// ---- fused attention v11: 8-wave block, c=256 (full) x i64, grid 256
// (1 block/CU). Halves barrier-iters/CU (32 vs 64), halves V traffic per
// work (V tile amortized over all 256 c), removes K compute dup.
// Wave w: S frags (is = 2*(w>>2)+{0,1}, js = w&3) -> 2 mfma16 + 8 exp2;
// PV c-rows [w*32,+32): acc[cs<2][is<4] += mfma16(V[cs][jc], P[is][jc]).
// Cross-barrier pipeline as v8: body t = {read P(t); S(t+1); K(t+2) pf;
// PV(t); V(t+2) pf; exp2/pack P(t+1); lgkm drain; s_barrier}.
#define MFMA16(A, B, C) __builtin_amdgcn_mfma_f32_16x16x32_bf16(A, B, C, 0, 0, 0)

#define ATTN_BODY(T, BUF, KC, KN, VA, VB, VC, VD)                              \
  {                                                                            \
    bf8 pf00 = *(const bf8*)&pS[BUF][ 0 + li][ 0 + lg8];                       \
    bf8 pf10 = *(const bf8*)&pS[BUF][16 + li][ 0 + lg8];                       \
    bf8 pf20 = *(const bf8*)&pS[BUF][32 + li][ 0 + lg8];                       \
    bf8 pf30 = *(const bf8*)&pS[BUF][48 + li][ 0 + lg8];                       \
    bf8 pf01 = *(const bf8*)&pS[BUF][ 0 + li][32 + lg8];                       \
    bf8 pf11 = *(const bf8*)&pS[BUF][16 + li][32 + lg8];                       \
    bf8 pf21 = *(const bf8*)&pS[BUF][32 + li][32 + lg8];                       \
    bf8 pf31 = *(const bf8*)&pS[BUF][48 + li][32 + lg8];                       \
    f4 s0 = {}, s1 = {};                                                       \
    if ((T) + 1 < NT_) {                                                       \
      s0 = MFMA16(KC, qf0, s0);                                                \
      s1 = MFMA16(KC, qf1, s1);                                                \
    }                                                                          \
    {                                                                          \
      int tn_ = (T) + 2 < NT_ ? (T) + 2 : NT_ - 1;                             \
      KN = *(const bf8*)(kp + (size_t)tn_ * 64 * 64);                          \
    }                                                                          \
    __builtin_amdgcn_s_setprio(1);                                             \
    acc[0][0] = MFMA16(VA, pf00, acc[0][0]);                                   \
    acc[0][1] = MFMA16(VA, pf10, acc[0][1]);                                   \
    acc[0][2] = MFMA16(VA, pf20, acc[0][2]);                                   \
    acc[0][3] = MFMA16(VA, pf30, acc[0][3]);                                   \
    acc[1][0] = MFMA16(VC, pf00, acc[1][0]);                                   \
    acc[1][1] = MFMA16(VC, pf10, acc[1][1]);                                   \
    acc[1][2] = MFMA16(VC, pf20, acc[1][2]);                                   \
    acc[1][3] = MFMA16(VC, pf30, acc[1][3]);                                   \
    acc[0][0] = MFMA16(VB, pf01, acc[0][0]);                                   \
    acc[0][1] = MFMA16(VB, pf11, acc[0][1]);                                   \
    acc[0][2] = MFMA16(VB, pf21, acc[0][2]);                                   \
    acc[0][3] = MFMA16(VB, pf31, acc[0][3]);                                   \
    acc[1][0] = MFMA16(VD, pf01, acc[1][0]);                                   \
    acc[1][1] = MFMA16(VD, pf11, acc[1][1]);                                   \
    acc[1][2] = MFMA16(VD, pf21, acc[1][2]);                                   \
    acc[1][3] = MFMA16(VD, pf31, acc[1][3]);                                   \
    __builtin_amdgcn_s_setprio(0);                                             \
    {                                                                          \
      int tn_ = (T) + 2 < NT_ ? (T) + 2 : NT_ - 1;                             \
      const __hip_bfloat16* vpn_ = vR + tn_ * 64;                              \
      VA = *(const bf8*)vpn_;                                                  \
      VB = *(const bf8*)(vpn_ + 32);                                           \
      VC = *(const bf8*)(vpn_ + 16 * VP_);                                     \
      VD = *(const bf8*)(vpn_ + 16 * VP_ + 32);                                \
    }                                                                          \
    if ((T) + 1 < NT_) {                                                       \
      _Pragma("unroll")                                                        \
      for (int m = 0; m < 4; ++m) {                                            \
        s0[m] = __builtin_amdgcn_exp2f(s0[m]);                                 \
        s1[m] = __builtin_amdgcn_exp2f(s1[m]);                                 \
      }                                                                        \
      lp0 += s0[0] + s0[1] + s0[2] + s0[3];                                    \
      lp1 += s1[0] + s1[1] + s1[2] + s1[3];                                    \
      bf4 t0, t1;                                                              \
      _Pragma("unroll")                                                        \
      for (int m = 0; m < 4; ++m) { t0[m] = (__bf16)s0[m]; t1[m] = (__bf16)s1[m]; } \
      *(bf4*)&pS[(BUF) ^ 1][is0 * 16 + li][js * 16 + lg4] = t0;                \
      *(bf4*)&pS[(BUF) ^ 1][is0 * 16 + 16 + li][js * 16 + lg4] = t1;           \
      asm volatile("s_waitcnt lgkmcnt(0)" ::: "memory");                       \
      __builtin_amdgcn_sched_barrier(0);                                       \
      __builtin_amdgcn_s_barrier();                                            \
      __builtin_amdgcn_sched_barrier(0);                                       \
    }                                                                          \
  }

__global__ __launch_bounds__(512, 2) void fused_attn(
    const __hip_bfloat16* __restrict__ qk,   // [b][n][64]: q 0..31, k 32..63
    const __hip_bfloat16* __restrict__ vbf,  // [b][c][VP_]
    const float* __restrict__ x, float* __restrict__ out) {
  __shared__ __attribute__((aligned(16))) __hip_bfloat16 pS[2][64][88];  // 22 KB
  __shared__ float lSp[4][4][16];
  int tid = threadIdx.x;
  int wv = tid >> 6, lane = tid & 63;       // 8 waves
  int li = lane & 15, lg = lane >> 4;
  int lg8 = lg * 8, lg4 = lg * 4;
  int is0 = (wv >> 2) * 2;                  // this wave's S i-frag pair
  int js = wv & 3;                          // this wave's S j-frag
  // XCD-pinning: b = blk&7 pins batch b's 32 blocks to one XCD's L2.
  int blk = blockIdx.x;
  int b = blk & 7;
  int i0 = (blk >> 3) * 64;

  const __hip_bfloat16* qkB = qk + (size_t)b * N_ * 64;
  // Q B-frags: col i = i0 + (is0+{0,1})*16 + li, k = h = lg*8+e
  bf8 qf0 = *(const bf8*)&qkB[(size_t)(i0 + is0 * 16 + li) * 64 + lg8];
  bf8 qf1 = *(const bf8*)&qkB[(size_t)(i0 + is0 * 16 + 16 + li) * 64 + lg8];
  // K A-frag base: row j = t*64 + js*16 + li, k = h (offset 32)
  const __hip_bfloat16* kp = qkB + (size_t)(js * 16 + li) * 64 + 32 + lg8;
  // V A-frag base: row c = wv*32 + cs*16 + li, k = j = t*64 + jc*32 + lg*8
  const __hip_bfloat16* vR =
      vbf + ((size_t)b * C_ + wv * 32 + li) * VP_ + lg8;

  // Prologue: K(0) transient; K(1)->kO; V(0)->vE; V(1)->vO.
  bf8 k00 = *(const bf8*)kp;
  bf8 kO = *(const bf8*)(kp + 64 * 64);
  bf8 kE;
  bf8 vEA = *(const bf8*)vR;
  bf8 vEB = *(const bf8*)(vR + 32);
  bf8 vEC = *(const bf8*)(vR + 16 * VP_);
  bf8 vED = *(const bf8*)(vR + 16 * VP_ + 32);
  bf8 vOA = *(const bf8*)(vR + 64);
  bf8 vOB = *(const bf8*)(vR + 64 + 32);
  bf8 vOC = *(const bf8*)(vR + 16 * VP_ + 64);
  bf8 vOD = *(const bf8*)(vR + 16 * VP_ + 64 + 32);

  f4 acc[2][4] = {};
  float lp0 = 0.f, lp1 = 0.f;

  // Prologue S(0): exp2, pack, publish P(0) -> pS[0]
  {
    f4 s0 = {}, s1 = {};
    s0 = MFMA16(k00, qf0, s0);
    s1 = MFMA16(k00, qf1, s1);
#pragma unroll
    for (int m = 0; m < 4; ++m) {
      s0[m] = __builtin_amdgcn_exp2f(s0[m]);
      s1[m] = __builtin_amdgcn_exp2f(s1[m]);
    }
    lp0 += s0[0] + s0[1] + s0[2] + s0[3];
    lp1 += s1[0] + s1[1] + s1[2] + s1[3];
    bf4 t0, t1;
#pragma unroll
    for (int m = 0; m < 4; ++m) { t0[m] = (__bf16)s0[m]; t1[m] = (__bf16)s1[m]; }
    *(bf4*)&pS[0][is0 * 16 + li][js * 16 + lg4] = t0;
    *(bf4*)&pS[0][is0 * 16 + 16 + li][js * 16 + lg4] = t1;
    asm volatile("s_waitcnt lgkmcnt(0)" ::: "memory");
    __builtin_amdgcn_sched_barrier(0);
    __builtin_amdgcn_s_barrier();
    __builtin_amdgcn_sched_barrier(0);
  }

  for (int tt = 0; tt < NT_; tt += 2) {
    ATTN_BODY(tt,     0, kO, kE, vEA, vEB, vEC, vED)
    ATTN_BODY(tt + 1, 1, kE, kO, vOA, vOB, vOC, vOD)
  }
#undef ATTN_BODY

  // Denominator: reduce over lg (shfl 16,32) -> per (js, is, li) partial in
  // LDS -> sum over 4 js.
  lp0 += __shfl_xor(lp0, 16); lp0 += __shfl_xor(lp0, 32);
  lp1 += __shfl_xor(lp1, 16); lp1 += __shfl_xor(lp1, 32);
  if (lane < 16) {
    lSp[js][is0][lane] = lp0;
    lSp[js][is0 + 1][lane] = lp1;
  }
  __syncthreads();
  float linv[4];
#pragma unroll
  for (int is = 0; is < 4; ++is)
    linv[is] = 1.0f / (lSp[0][is][li] + lSp[1][is][li] +
                       lSp[2][is][li] + lSp[3][is][li]);

  const float* xr = x + (size_t)b * C_ * N_;
  float* op = out + (size_t)b * C_ * N_;
#pragma unroll
  for (int cs = 0; cs < 2; ++cs)
#pragma unroll
    for (int m = 0; m < 4; ++m) {
      int c = wv * 32 + cs * 16 + lg4 + m;
      size_t base = (size_t)c * N_ + i0;
      op[base +  0 + li] = acc[cs][0][m] * linv[0] + xr[base +  0 + li];
      op[base + 16 + li] = acc[cs][1][m] * linv[1] + xr[base + 16 + li];
      op[base + 32 + li] = acc[cs][2][m] * linv[2] + xr[base + 32 + li];
      op[base + 48 + li] = acc[cs][3][m] * linv[3] + xr[base + 48 + li];
    }
}

extern "C" void kernel_launch(void* const* d_in, const int* in_sizes, int n_in,
                              void* d_out, int out_size, void* d_ws, size_t ws_size,
                              hipStream_t stream) {
  const float* x  = (const float*)d_in[0];
  const float* wq = (const float*)d_in[1];
  const float* bq = (const float*)d_in[2];
  const float* wk = (const float*)d_in[3];
  const float* bk = (const float*)d_in[4];
  const float* wv = (const float*)d_in[5];
  const float* bv = (const float*)d_in[6];
  float* out = (float*)d_out;

  char* ws = (char*)d_ws;
  __hip_bfloat16* qkb = (__hip_bfloat16*)ws;                        // 2 MiB [b][n][64]
  __hip_bfloat16* vbf = (__hip_bfloat16*)(ws + (2u << 20));         // 8.06 MiB [b][c][VP_]
  __hip_bfloat16* wpk = (__hip_bfloat16*)(ws + 10551296u);          // 160 KiB [320][256]
  float*          bpk = (float*)(ws + 10551296u + 163840u);

  pack_kernel<<<dim3(320), 256, 0, stream>>>(wq, wk, wv, bq, bk, bv, wpk, bpk);
  proj_kernel<<<dim3(N_ / 32, B_), 256, 0, stream>>>(x, wpk, bpk, vbf, qkb);
  fused_attn<<<dim3(256), 512, 0, stream>>>(qkb, vbf, x, out);
}